// Round 12
// baseline (189.708 us; speedup 1.0000x reference)
//
#include <hip/hip_runtime.h>
#include <math.h>

#define N_ROWS 8192
#define D_DIM  512
#define C_CLS  100
#define UVS    24            // uv row-slices
#define UVR    342           // rows per slice (24*342 >= 8192)

typedef unsigned short u16;
typedef unsigned int u32;
typedef __attribute__((ext_vector_type(8))) _Float16 half8;
typedef __attribute__((ext_vector_type(4))) float floatx4;

// ---------------- ws layout (float offsets), ~30.3 MB ----------------
#define WS_G      0              // 512*512 fp32 (written by kR)
#define WS_GP     262144         // 16*10*16384 fp32 splitK partials
#define WS_INV    2883584        // 8192
#define WS_WV     2891776        // 8192
#define WS_CLS    2899968        // 8192 (int)
#define WS_CNTP   2908160        // 24*128 int count partials
#define WS_UP     2911232        // 24*8*6400 u partials
#define WS_VP     4140032        // 24*8*6400 v partials
#define WS_U      5368832        // 100*512
#define WS_V      5420032        // 100*512
#define WS_ZTH    5471232        // 512*8192 fp16

typedef const __attribute__((address_space(1))) u32* gp32;
typedef __attribute__((address_space(3))) u32* lp32;
__device__ __forceinline__ void cp16(const u16* g, u16* l) {
    __builtin_amdgcn_global_load_lds((gp32)g, (lp32)l, 16, 0, 0);
}

__device__ __forceinline__ u16 f2h(float v) {
    _Float16 h = (_Float16)v;
    return *(u16*)&h;
}

// ===== kA: bx<1024 softmax (8 rows) | [1024,1280) norm+cvt+transpose =====
__global__ __launch_bounds__(256) void kA(const float* __restrict__ logits,
        const float* __restrict__ x, float* __restrict__ wv, int* __restrict__ cls,
        float* __restrict__ inv, u16* __restrict__ zth) {
    __shared__ float xs[32 * 516];      // 66 KB fp32 stripe
    __shared__ float ns[8][32];
    __shared__ float sv_s[32];
    int bx = blockIdx.x, t = threadIdx.x;
    if (bx < 1024) {
        int lane = t & 63;
        int row0 = (bx << 3) + ((t >> 6) << 1);
        #pragma unroll
        for (int rr = 0; rr < 2; ++rr) {
            int row = row0 + rr;
            const float* lrow = logits + (size_t)row * C_CLS;
            float v1 = lrow[lane];
            bool has2 = (lane + 64) < C_CLS;
            float v2 = has2 ? lrow[lane + 64] : -INFINITY;
            float m; int idx;
            if (v2 > v1) { m = v2; idx = lane + 64; } else { m = v1; idx = lane; }
            #pragma unroll
            for (int off = 32; off >= 1; off >>= 1) {
                float om = __shfl_down(m, off);
                int   oi = __shfl_down(idx, off);
                if (om > m || (om == m && oi < idx)) { m = om; idx = oi; }
            }
            m = __shfl(m, 0);
            idx = __shfl(idx, 0);
            float s = expf(v1 - m) + (has2 ? expf(v2 - m) : 0.0f);
            #pragma unroll
            for (int off = 32; off >= 1; off >>= 1) s += __shfl_down(s, off);
            if (lane == 0) {
                wv[row] = 1.0f / s;
                cls[row] = idx;
            }
        }
        return;
    }
    // -------- 32-row stripe: stage to LDS, norms, fp16 convert + transpose --
    int r0 = (bx - 1024) << 5;
    const float* src = x + (size_t)r0 * D_DIM;
    #pragma unroll
    for (int i = 0; i < 16; ++i) {
        int e = i * 1024 + t * 4;
        int r = e >> 9, c = e & 511;
        *(float4*)&xs[r * 516 + c] = *(const float4*)&src[e];
    }
    __syncthreads();
    {
        int r = t & 31, seg = t >> 5;
        const float* row = &xs[r * 516 + seg * 64];
        float ss = 0.f;
        #pragma unroll
        for (int jj = 0; jj < 64; ++jj) { float v = row[jj]; ss += v * v; }
        ns[seg][r] = ss;
    }
    __syncthreads();
    if (t < 32) {
        float ss = ns[0][t] + ns[1][t] + ns[2][t] + ns[3][t]
                 + ns[4][t] + ns[5][t] + ns[6][t] + ns[7][t];
        float iv = 1.0f / fmaxf(sqrtf(ss), 1e-8f);
        inv[r0 + t] = iv;
        sv_s[t] = sqrtf(iv);
    }
    __syncthreads();
    int c = t >> 2, rq = (t & 3) * 8;
    float svl[8];
    #pragma unroll
    for (int ii = 0; ii < 8; ++ii) svl[ii] = sv_s[rq + ii];
    #pragma unroll
    for (int ct = 0; ct < 8; ++ct) {
        int d = ct * 64 + c;
        u16 o[8];
        #pragma unroll
        for (int ii = 0; ii < 8; ++ii)
            o[ii] = f2h(xs[(rq + ii) * 516 + d] * svl[ii]);
        uint4 val = make_uint4((u32)o[0] | ((u32)o[1] << 16),
                               (u32)o[2] | ((u32)o[3] << 16),
                               (u32)o[4] | ((u32)o[5] << 16),
                               (u32)o[6] | ((u32)o[7] << 16));
        *(uint4*)&zth[(size_t)d * N_ROWS + r0 + rq] = val;
    }
}

// ===== kC: blocks 0..159 fp16 GEMM (splitK=16, store partials);
//           blocks 160..351: uv class-accumulation via LDS atomics =====
__global__ __launch_bounds__(256) void kC(const u16* __restrict__ zth,
        const float* __restrict__ x, const float* __restrict__ inv,
        const float* __restrict__ wv, const int* __restrict__ cls,
        float* __restrict__ Gp, float* __restrict__ up, float* __restrict__ vp,
        int* __restrict__ cntp) {
    __shared__ __attribute__((aligned(16))) union {
        struct { u16 Ah[128 * 32], Bh[128 * 32]; } g;              // 16 KB
        struct { float us[C_CLS * 64], vs[C_CLS * 64]; int cs[128]; } uv; // 51.7 KB
    } sm;
    int bx = blockIdx.x, t = threadIdx.x;
    if (bx >= 160) {
        int idx = bx - 160;                 // 0..191
        int s = idx >> 3, jc = idx & 7;     // slice, col-chunk
        int lo = s * UVR;
        int hi = min(N_ROWS, lo + UVR);
        for (int k = t; k < C_CLS * 64; k += 256) {
            sm.uv.us[k] = 0.f;
            sm.uv.vs[k] = 0.f;
        }
        if (t < 128) sm.uv.cs[t] = 0;
        __syncthreads();
        int w = t >> 6, l = t & 63;
        int j = jc * 64 + l;
        for (int m = lo + w; m < hi; m += 4) {
            int c = cls[m];
            float wm = wv[m];
            float wi = wm * inv[m];
            float xv = x[(size_t)m * D_DIM + j];
            atomicAdd(&sm.uv.us[c * 64 + l], wi * xv);
            atomicAdd(&sm.uv.vs[c * 64 + l], wm * xv);
            if (jc == 0 && l == 0) atomicAdd(&sm.uv.cs[c], 1);
        }
        __syncthreads();
        size_t base = (size_t)idx * (C_CLS * 64);
        for (int k = t; k < C_CLS * 64; k += 256) {
            up[base + k] = sm.uv.us[k];
            vp[base + k] = sm.uv.vs[k];
        }
        if (jc == 0 && t < 128) cntp[s * 128 + t] = sm.uv.cs[t];
        return;
    }
    int tile = bx % 10;
    int p = bx / 10;                    // 0..15
    int ti = tile < 4 ? 0 : (tile < 7 ? 1 : (tile < 9 ? 2 : 3));
    int tj = tile - (ti == 0 ? 0 : (ti == 1 ? 3 : (ti == 2 ? 5 : 6)));
    int i0 = ti << 7, j0 = tj << 7;
    bool diag = (ti == tj);
    int kb = p << 9;                    // K-chunk of 512
    int w = t >> 6, l = t & 63;
    int srow = t >> 2, scol = (t & 3) << 3;
    int lm = l & 15, lg = l >> 4;
    floatx4 acc[4][4];
    #pragma unroll
    for (int mi = 0; mi < 4; ++mi)
        #pragma unroll
        for (int ni = 0; ni < 4; ++ni) acc[mi][ni] = (floatx4){0.f, 0.f, 0.f, 0.f};
    int d0 = srow * 32 + scol;
    int d1 = (64 + srow) * 32 + scol;
    const size_t ga0 = (size_t)(i0 + srow) * N_ROWS + kb + scol;
    const size_t ga1 = (size_t)(i0 + 64 + srow) * N_ROWS + kb + scol;
    const size_t gb0 = (size_t)(j0 + srow) * N_ROWS + kb + scol;
    const size_t gb1 = (size_t)(j0 + 64 + srow) * N_ROWS + kb + scol;
    const u16* Bhs = diag ? sm.g.Ah : sm.g.Bh;
    for (int s = 0; s < 16; ++s) {
        int ks = s << 5;
        cp16(zth + ga0 + ks, sm.g.Ah + d0);
        cp16(zth + ga1 + ks, sm.g.Ah + d1);
        if (!diag) {
            cp16(zth + gb0 + ks, sm.g.Bh + d0);
            cp16(zth + gb1 + ks, sm.g.Bh + d1);
        }
        __syncthreads();
        half8 ah[4], bh[4];
        #pragma unroll
        for (int mi = 0; mi < 4; ++mi) {
            int off = (((w & 1) << 6) + (mi << 4) + lm) * 32 + (lg << 3);
            ah[mi] = *(const half8*)&sm.g.Ah[off];
        }
        #pragma unroll
        for (int ni = 0; ni < 4; ++ni) {
            int off = (((w >> 1) << 6) + (ni << 4) + lm) * 32 + (lg << 3);
            bh[ni] = *(const half8*)&Bhs[off];
        }
        #pragma unroll
        for (int mi = 0; mi < 4; ++mi)
            #pragma unroll
            for (int ni = 0; ni < 4; ++ni)
                acc[mi][ni] = __builtin_amdgcn_mfma_f32_16x16x32_f16(ah[mi], bh[ni], acc[mi][ni], 0, 0, 0);
        __syncthreads();
    }
    float* Gb = Gp + ((size_t)(p * 10 + tile) << 14);
    #pragma unroll
    for (int mi = 0; mi < 4; ++mi) {
        int row0 = ((w & 1) << 6) + (mi << 4) + (lg << 2);
        #pragma unroll
        for (int ni = 0; ni < 4; ++ni) {
            int col = ((w >> 1) << 6) + (ni << 4) + lm;
            #pragma unroll
            for (int r = 0; r < 4; ++r)
                Gb[(size_t)(row0 + r) * 128 + col] = acc[mi][ni][r];
        }
    }
}

// ===== kR: bx<1024: G reduce (mirror); bx>=1024: uv partial reduce =====
__global__ __launch_bounds__(256) void kR(const float* __restrict__ Gp,
        const float* __restrict__ up, const float* __restrict__ vp,
        float* __restrict__ G, float* __restrict__ u_arr, float* __restrict__ v_arr) {
    int bx = blockIdx.x, t = threadIdx.x;
    if (bx < 1024) {
        int i = bx * 256 + t;                  // 0..262143
        int r = i >> 9, c = i & 511;
        int tr = r >> 7, tc = c >> 7, rr = r & 127, cc = c & 127;
        if (tr > tc) { int tmp = tr; tr = tc; tc = tmp; tmp = rr; rr = cc; cc = tmp; }
        int tid = tr * 4 + tc - ((tr * (tr + 1)) >> 1);
        const float* src = Gp + ((size_t)tid << 14) + rr * 128 + cc;
        float s = 0.f;
        #pragma unroll
        for (int p = 0; p < 16; ++p) s += src[(size_t)p * 163840];
        G[i] = s;
        return;
    }
    int eid = (bx - 1024) * 256 + t;           // 0..102399
    int e = (eid < C_CLS * D_DIM) ? eid : eid - C_CLS * D_DIM;
    int c = e >> 9, j = e & 511;
    int jc = j >> 6, l = j & 63;
    const float* src = (eid < C_CLS * D_DIM) ? up : vp;
    float s = 0.f;
    #pragma unroll
    for (int sl = 0; sl < UVS; ++sl)
        s += src[(size_t)(sl * 8 + jc) * (C_CLS * 64) + c * 64 + l];
    if (eid < C_CLS * D_DIM) u_arr[e] = s;
    else                     v_arr[e] = s;
}

// ===== kD: protos, tiled for G-reuse: 13 class-groups x 16 col-panels =====
__global__ __launch_bounds__(256) void kD(const float* __restrict__ u_arr,
        const float* __restrict__ v_arr, const int* __restrict__ cntp,
        const float* __restrict__ G, float* __restrict__ out) {
    __shared__ float us[8][512];
    __shared__ int cnt_s[8];
    int g = blockIdx.x >> 4;            // 0..12
    int panel = blockIdx.x & 15;        // 0..15
    int t = threadIdx.x;
    if (t < 8) {
        int cc = g * 8 + t;
        int n = 0;
        if (cc < C_CLS)
            for (int sl = 0; sl < UVS; ++sl) n += cntp[sl * 128 + cc];
        cnt_s[t] = n;
    }
    for (int idx = t; idx < 8 * 512; idx += 256) {
        int ci = idx >> 9, k = idx & 511;
        int cc = g * 8 + ci;
        us[ci][k] = (cc < C_CLS) ? u_arr[(size_t)cc * D_DIM + k] : 0.f;
    }
    __syncthreads();
    int ci = t >> 5, cj = t & 31;
    int c = g * 8 + ci;
    int j = panel * 32 + cj;
    float acc = 0.f;
    #pragma unroll 8
    for (int k = 0; k < D_DIM; ++k)
        acc += us[ci][k] * G[(size_t)k * D_DIM + j];
    if (c < C_CLS) {
        int n = cnt_s[ci];
        float s = (n > 0) ? 1.0f / (float)n : 0.0f;
        out[(size_t)c * D_DIM + j] = (v_arr[(size_t)c * D_DIM + j] + acc) * s;
    }
}

// ===== kE: inter[i,j,:] = proto[j] - proto[i]; 4 pairs/block =====
__global__ __launch_bounds__(256) void kE(const float* __restrict__ proto,
                                          float* __restrict__ inter) {
    int pair = blockIdx.x * 4 + (threadIdx.x >> 6);
    int i = pair / C_CLS;
    int j = pair - i * C_CLS;
    int d = (threadIdx.x & 63) << 3;
    float4 pj0 = *(const float4*)&proto[j * D_DIM + d];
    float4 pj1 = *(const float4*)&proto[j * D_DIM + d + 4];
    float4 pi0 = *(const float4*)&proto[i * D_DIM + d];
    float4 pi1 = *(const float4*)&proto[i * D_DIM + d + 4];
    float4 r0, r1;
    r0.x = pj0.x - pi0.x; r0.y = pj0.y - pi0.y; r0.z = pj0.z - pi0.z; r0.w = pj0.w - pi0.w;
    r1.x = pj1.x - pi1.x; r1.y = pj1.y - pi1.y; r1.z = pj1.z - pi1.z; r1.w = pj1.w - pi1.w;
    *(float4*)&inter[(size_t)pair * D_DIM + d]     = r0;
    *(float4*)&inter[(size_t)pair * D_DIM + d + 4] = r1;
}

extern "C" void kernel_launch(void* const* d_in, const int* in_sizes, int n_in,
                              void* d_out, int out_size, void* d_ws, size_t ws_size,
                              hipStream_t stream) {
    const float* x      = (const float*)d_in[0];   // [8192, 512]
    const float* logits = (const float*)d_in[1];   // [8192, 100]
    float* out = (float*)d_out;
    float* ws  = (float*)d_ws;
    float* G     = ws + WS_G;
    float* Gp    = ws + WS_GP;
    float* inv   = ws + WS_INV;
    float* wv    = ws + WS_WV;
    int*   cls   = (int*)(ws + WS_CLS);
    int*   cntp  = (int*)(ws + WS_CNTP);
    float* up    = ws + WS_UP;
    float* vp    = ws + WS_VP;
    float* u_arr = ws + WS_U;
    float* v_arr = ws + WS_V;
    u16* zth = (u16*)(ws + WS_ZTH);

    kA<<<1280, 256, 0, stream>>>(logits, x, wv, cls, inv, zth);
    kC<<<352, 256, 0, stream>>>(zth, x, inv, wv, cls, Gp, up, vp, cntp);
    kR<<<1424, 256, 0, stream>>>(Gp, up, vp, G, u_arr, v_arr);
    kD<<<208, 256, 0, stream>>>(u_arr, v_arr, cntp, G, out);
    kE<<<C_CLS * C_CLS / 4, 256, 0, stream>>>(out, out + C_CLS * D_DIM);
}

// Round 13
// 169.777 us; speedup vs baseline: 1.1174x; 1.1174x over previous
//
#include <hip/hip_runtime.h>
#include <math.h>

#define N_ROWS 8192
#define D_DIM  512
#define C_CLS  100

typedef unsigned short u16;
typedef unsigned int u32;
typedef __attribute__((ext_vector_type(8))) _Float16 half8;
typedef __attribute__((ext_vector_type(4))) float floatx4;

// ---------------- ws layout (float offsets), ~31 MB ----------------
#define WS_G      0              // 512*512 fp32 (written by kR)
#define WS_GP     262144         // 32*10*16384 fp32 splitK partials
#define WS_INV    5505024        // 8192
#define WS_WV     5513216        // 8192
#define WS_CLS    5521408        // 8192 (int)
#define WS_CNT    5529600        // 128 (int)
#define WS_OFFS   5529728        // 128 (int)
#define WS_ORDER  5529856        // 8192 (int)
#define WS_U      5538048        // 100*512
#define WS_V      5589248        // 100*512
#define WS_ZTH    5640448        // 512*8192 fp16

typedef const __attribute__((address_space(1))) u32* gp32;
typedef __attribute__((address_space(3))) u32* lp32;
__device__ __forceinline__ void cp16(const u16* g, u16* l) {
    __builtin_amdgcn_global_load_lds((gp32)g, (lp32)l, 16, 0, 0);
}

__device__ __forceinline__ u16 f2h(float v) {
    _Float16 h = (_Float16)v;
    return *(u16*)&h;
}

// ===== kA: bx<1024 softmax (8 rows) | [1024,1280) norm+cvt+transpose =====
__global__ __launch_bounds__(256) void kA(const float* __restrict__ logits,
        const float* __restrict__ x, float* __restrict__ wv, int* __restrict__ cls,
        float* __restrict__ inv, u16* __restrict__ zth) {
    __shared__ float xs[32 * 516];      // 66 KB fp32 stripe
    __shared__ float ns[8][32];
    __shared__ float sv_s[32];
    int bx = blockIdx.x, t = threadIdx.x;
    if (bx < 1024) {
        int lane = t & 63;
        int row0 = (bx << 3) + ((t >> 6) << 1);
        #pragma unroll
        for (int rr = 0; rr < 2; ++rr) {
            int row = row0 + rr;
            const float* lrow = logits + (size_t)row * C_CLS;
            float v1 = lrow[lane];
            bool has2 = (lane + 64) < C_CLS;
            float v2 = has2 ? lrow[lane + 64] : -INFINITY;
            float m; int idx;
            if (v2 > v1) { m = v2; idx = lane + 64; } else { m = v1; idx = lane; }
            #pragma unroll
            for (int off = 32; off >= 1; off >>= 1) {
                float om = __shfl_down(m, off);
                int   oi = __shfl_down(idx, off);
                if (om > m || (om == m && oi < idx)) { m = om; idx = oi; }
            }
            m = __shfl(m, 0);
            idx = __shfl(idx, 0);
            float s = expf(v1 - m) + (has2 ? expf(v2 - m) : 0.0f);
            #pragma unroll
            for (int off = 32; off >= 1; off >>= 1) s += __shfl_down(s, off);
            if (lane == 0) {
                wv[row] = 1.0f / s;
                cls[row] = idx;
            }
        }
        return;
    }
    // -------- 32-row stripe: stage to LDS, norms, fp16 convert + transpose --
    int r0 = (bx - 1024) << 5;
    const float* src = x + (size_t)r0 * D_DIM;
    #pragma unroll
    for (int i = 0; i < 16; ++i) {
        int e = i * 1024 + t * 4;
        int r = e >> 9, c = e & 511;
        *(float4*)&xs[r * 516 + c] = *(const float4*)&src[e];
    }
    __syncthreads();
    {
        int r = t & 31, seg = t >> 5;
        const float* row = &xs[r * 516 + seg * 64];
        float ss = 0.f;
        #pragma unroll
        for (int jj = 0; jj < 64; ++jj) { float v = row[jj]; ss += v * v; }
        ns[seg][r] = ss;
    }
    __syncthreads();
    if (t < 32) {
        float ss = ns[0][t] + ns[1][t] + ns[2][t] + ns[3][t]
                 + ns[4][t] + ns[5][t] + ns[6][t] + ns[7][t];
        float iv = 1.0f / fmaxf(sqrtf(ss), 1e-8f);
        inv[r0 + t] = iv;
        sv_s[t] = sqrtf(iv);
    }
    __syncthreads();
    int c = t >> 2, rq = (t & 3) * 8;
    float svl[8];
    #pragma unroll
    for (int ii = 0; ii < 8; ++ii) svl[ii] = sv_s[rq + ii];
    #pragma unroll
    for (int ct = 0; ct < 8; ++ct) {
        int d = ct * 64 + c;
        u16 o[8];
        #pragma unroll
        for (int ii = 0; ii < 8; ++ii)
            o[ii] = f2h(xs[(rq + ii) * 516 + d] * svl[ii]);
        uint4 val = make_uint4((u32)o[0] | ((u32)o[1] << 16),
                               (u32)o[2] | ((u32)o[3] << 16),
                               (u32)o[4] | ((u32)o[5] << 16),
                               (u32)o[6] | ((u32)o[7] << 16));
        *(uint4*)&zth[(size_t)d * N_ROWS + r0 + rq] = val;
    }
}

// ===== kB: single-block (1024 thr) class histogram + scan + scatter =====
__global__ __launch_bounds__(1024) void kB(const int* __restrict__ cls,
        int* __restrict__ cnt, int* __restrict__ offs, int* __restrict__ order) {
    __shared__ int hist[128], scan_s[128], cur[128];
    int t = threadIdx.x;
    if (t < 128) hist[t] = 0;
    __syncthreads();
    for (int m = t; m < N_ROWS; m += 1024) atomicAdd(&hist[cls[m]], 1);
    __syncthreads();
    if (t < 128) scan_s[t] = hist[t];
    __syncthreads();
    #pragma unroll
    for (int d = 1; d < 128; d <<= 1) {
        int add = (t < 128 && t >= d) ? scan_s[t - d] : 0;
        __syncthreads();
        if (t < 128) scan_s[t] += add;
        __syncthreads();
    }
    if (t < 128) {
        int off0 = scan_s[t] - hist[t];
        cur[t] = off0;
        offs[t] = off0;
        cnt[t] = hist[t];
    }
    __syncthreads();
    for (int m = t; m < N_ROWS; m += 1024) {
        int p = atomicAdd(&cur[cls[m]], 1);
        order[p] = m;
    }
}

// ===== kC: blocks 0..319 fp16 GEMM (splitK=32, store partials); 320..1119 uv ==
__global__ __launch_bounds__(256) void kC(const u16* __restrict__ zth,
        const float* __restrict__ x, const float* __restrict__ inv,
        const float* __restrict__ wv, const int* __restrict__ order,
        const int* __restrict__ offs, const int* __restrict__ cnt,
        float* __restrict__ Gp, float* __restrict__ u_arr, float* __restrict__ v_arr) {
    __shared__ __attribute__((aligned(16))) union {
        struct { u16 Ah[128 * 32], Bh[128 * 32]; } g;      // 16 KB
        struct { float us[4][64], vs[4][64]; } uv;
    } sm;
    int bx = blockIdx.x, t = threadIdx.x;
    if (bx >= 320) {
        int idx = bx - 320;
        int c = idx >> 3, jc = idx & 7;
        int g = t >> 6, lane = t & 63;
        int j = jc * 64 + lane;
        int n = cnt[c], o = offs[c];
        float ua = 0.f, va = 0.f;
        for (int p = g; p < n; p += 4) {
            int m = order[o + p];
            float wm = wv[m];
            float wi = wm * inv[m];
            float xv = x[(size_t)m * D_DIM + j];
            ua += wi * xv; va += wm * xv;
        }
        sm.uv.us[g][lane] = ua; sm.uv.vs[g][lane] = va;
        __syncthreads();
        if (g == 0) {
            u_arr[(size_t)c * D_DIM + j] = sm.uv.us[0][lane] + sm.uv.us[1][lane] + sm.uv.us[2][lane] + sm.uv.us[3][lane];
            v_arr[(size_t)c * D_DIM + j] = sm.uv.vs[0][lane] + sm.uv.vs[1][lane] + sm.uv.vs[2][lane] + sm.uv.vs[3][lane];
        }
        return;
    }
    int tile = bx % 10;
    int p = bx / 10;                    // 0..31
    int ti = tile < 4 ? 0 : (tile < 7 ? 1 : (tile < 9 ? 2 : 3));
    int tj = tile - (ti == 0 ? 0 : (ti == 1 ? 3 : (ti == 2 ? 5 : 6)));
    int i0 = ti << 7, j0 = tj << 7;
    bool diag = (ti == tj);
    int kb = p << 8;                    // K-chunk of 256
    int w = t >> 6, l = t & 63;
    int srow = t >> 2, scol = (t & 3) << 3;
    int lm = l & 15, lg = l >> 4;
    floatx4 acc[4][4];
    #pragma unroll
    for (int mi = 0; mi < 4; ++mi)
        #pragma unroll
        for (int ni = 0; ni < 4; ++ni) acc[mi][ni] = (floatx4){0.f, 0.f, 0.f, 0.f};
    int d0 = srow * 32 + scol;
    int d1 = (64 + srow) * 32 + scol;
    const size_t ga0 = (size_t)(i0 + srow) * N_ROWS + kb + scol;
    const size_t ga1 = (size_t)(i0 + 64 + srow) * N_ROWS + kb + scol;
    const size_t gb0 = (size_t)(j0 + srow) * N_ROWS + kb + scol;
    const size_t gb1 = (size_t)(j0 + 64 + srow) * N_ROWS + kb + scol;
    const u16* Bhs = diag ? sm.g.Ah : sm.g.Bh;
    for (int s = 0; s < 8; ++s) {
        int ks = s << 5;
        cp16(zth + ga0 + ks, sm.g.Ah + d0);
        cp16(zth + ga1 + ks, sm.g.Ah + d1);
        if (!diag) {
            cp16(zth + gb0 + ks, sm.g.Bh + d0);
            cp16(zth + gb1 + ks, sm.g.Bh + d1);
        }
        __syncthreads();
        half8 ah[4], bh[4];
        #pragma unroll
        for (int mi = 0; mi < 4; ++mi) {
            int off = (((w & 1) << 6) + (mi << 4) + lm) * 32 + (lg << 3);
            ah[mi] = *(const half8*)&sm.g.Ah[off];
        }
        #pragma unroll
        for (int ni = 0; ni < 4; ++ni) {
            int off = (((w >> 1) << 6) + (ni << 4) + lm) * 32 + (lg << 3);
            bh[ni] = *(const half8*)&Bhs[off];
        }
        #pragma unroll
        for (int mi = 0; mi < 4; ++mi)
            #pragma unroll
            for (int ni = 0; ni < 4; ++ni)
                acc[mi][ni] = __builtin_amdgcn_mfma_f32_16x16x32_f16(ah[mi], bh[ni], acc[mi][ni], 0, 0, 0);
        __syncthreads();
    }
    float* Gb = Gp + ((size_t)(p * 10 + tile) << 14);
    #pragma unroll
    for (int mi = 0; mi < 4; ++mi) {
        int row0 = ((w & 1) << 6) + (mi << 4) + (lg << 2);
        #pragma unroll
        for (int ni = 0; ni < 4; ++ni) {
            int col = ((w >> 1) << 6) + (ni << 4) + lm;
            #pragma unroll
            for (int r = 0; r < 4; ++r)
                Gb[(size_t)(row0 + r) * 128 + col] = acc[mi][ni][r];
        }
    }
}

// ===== kR: G[r][c] = sum_p Gp[p][uppertile(r,c)] (mirror lower) =====
__global__ __launch_bounds__(256) void kR(const float* __restrict__ Gp,
                                          float* __restrict__ G) {
    int i = blockIdx.x * 256 + threadIdx.x;      // 0..262143
    int r = i >> 9, c = i & 511;
    int tr = r >> 7, tc = c >> 7, rr = r & 127, cc = c & 127;
    if (tr > tc) { int tmp = tr; tr = tc; tc = tmp; tmp = rr; rr = cc; cc = tmp; }
    int tid = tr * 4 + tc - ((tr * (tr + 1)) >> 1);
    const float* src = Gp + ((size_t)tid << 14) + rr * 128 + cc;
    float s = 0.f;
    #pragma unroll
    for (int p = 0; p < 32; ++p) s += src[(size_t)p * 163840];
    G[i] = s;
}

// ===== kD: protos, tiled for G-reuse: 13 class-groups x 16 col-panels =====
__global__ __launch_bounds__(256) void kD(const float* __restrict__ u_arr,
        const float* __restrict__ v_arr, const int* __restrict__ cnt,
        const float* __restrict__ G, float* __restrict__ out) {
    __shared__ float us[8][512];
    int g = blockIdx.x >> 4;            // 0..12
    int panel = blockIdx.x & 15;        // 0..15
    int t = threadIdx.x;
    for (int idx = t; idx < 8 * 512; idx += 256) {
        int ci = idx >> 9, k = idx & 511;
        int cc = g * 8 + ci;
        us[ci][k] = (cc < C_CLS) ? u_arr[(size_t)cc * D_DIM + k] : 0.f;
    }
    __syncthreads();
    int ci = t >> 5, cj = t & 31;
    int c = g * 8 + ci;
    int j = panel * 32 + cj;
    float acc = 0.f;
    #pragma unroll 8
    for (int k = 0; k < D_DIM; ++k)
        acc += us[ci][k] * G[(size_t)k * D_DIM + j];
    if (c < C_CLS) {
        int n = cnt[c];
        float s = (n > 0) ? 1.0f / (float)n : 0.0f;
        out[(size_t)c * D_DIM + j] = (v_arr[(size_t)c * D_DIM + j] + acc) * s;
    }
}

// ===== kE: inter[i,j,:] = proto[j] - proto[i]; 4 pairs/block =====
__global__ __launch_bounds__(256) void kE(const float* __restrict__ proto,
                                          float* __restrict__ inter) {
    int pair = blockIdx.x * 4 + (threadIdx.x >> 6);
    int i = pair / C_CLS;
    int j = pair - i * C_CLS;
    int d = (threadIdx.x & 63) << 3;
    float4 pj0 = *(const float4*)&proto[j * D_DIM + d];
    float4 pj1 = *(const float4*)&proto[j * D_DIM + d + 4];
    float4 pi0 = *(const float4*)&proto[i * D_DIM + d];
    float4 pi1 = *(const float4*)&proto[i * D_DIM + d + 4];
    float4 r0, r1;
    r0.x = pj0.x - pi0.x; r0.y = pj0.y - pi0.y; r0.z = pj0.z - pi0.z; r0.w = pj0.w - pi0.w;
    r1.x = pj1.x - pi1.x; r1.y = pj1.y - pi1.y; r1.z = pj1.z - pi1.z; r1.w = pj1.w - pi1.w;
    *(float4*)&inter[(size_t)pair * D_DIM + d]     = r0;
    *(float4*)&inter[(size_t)pair * D_DIM + d + 4] = r1;
}

extern "C" void kernel_launch(void* const* d_in, const int* in_sizes, int n_in,
                              void* d_out, int out_size, void* d_ws, size_t ws_size,
                              hipStream_t stream) {
    const float* x      = (const float*)d_in[0];   // [8192, 512]
    const float* logits = (const float*)d_in[1];   // [8192, 100]
    float* out = (float*)d_out;
    float* ws  = (float*)d_ws;
    float* G     = ws + WS_G;
    float* Gp    = ws + WS_GP;
    float* inv   = ws + WS_INV;
    float* wv    = ws + WS_WV;
    int*   cls   = (int*)(ws + WS_CLS);
    int*   cnt   = (int*)(ws + WS_CNT);
    int*   offs  = (int*)(ws + WS_OFFS);
    int*   order = (int*)(ws + WS_ORDER);
    float* u_arr = ws + WS_U;
    float* v_arr = ws + WS_V;
    u16* zth = (u16*)(ws + WS_ZTH);

    kA<<<1280, 256, 0, stream>>>(logits, x, wv, cls, inv, zth);
    kB<<<1, 1024, 0, stream>>>(cls, cnt, offs, order);
    kC<<<1120, 256, 0, stream>>>(zth, x, inv, wv, order, offs, cnt, Gp, u_arr, v_arr);
    kR<<<1024, 256, 0, stream>>>(Gp, G);
    kD<<<208, 256, 0, stream>>>(u_arr, v_arr, cnt, G, out);
    kE<<<C_CLS * C_CLS / 4, 256, 0, stream>>>(out, out + C_CLS * D_DIM);
}

// Round 14
// 168.753 us; speedup vs baseline: 1.1242x; 1.0061x over previous
//
#include <hip/hip_runtime.h>
#include <math.h>

#define N_ROWS 8192
#define D_DIM  512
#define C_CLS  100

typedef unsigned short u16;
typedef unsigned int u32;
typedef __attribute__((ext_vector_type(8))) _Float16 half8;
typedef __attribute__((ext_vector_type(4))) float floatx4;

// ---------------- ws layout (float offsets), ~31 MB ----------------
#define WS_G      0              // 512*512 fp32 (written by kR)
#define WS_GP     262144         // 32*10*16384 fp32 splitK partials
#define WS_INV    5505024        // 8192
#define WS_WV     5513216        // 8192
#define WS_CLS    5521408        // 8192 (int)
#define WS_CNT    5529600        // 128 (int)
#define WS_OFFS   5529728        // 128 (int)
#define WS_ORDER  5529856        // 8192 (int)
#define WS_U      5538048        // 100*512
#define WS_V      5589248        // 100*512
#define WS_ZTH    5640448        // 512*8192 fp16

#define LDA 517                  // kA LDS stride: 4-way -> <=2-way conflicts

typedef const __attribute__((address_space(1))) u32* gp32;
typedef __attribute__((address_space(3))) u32* lp32;
__device__ __forceinline__ void cp16(const u16* g, u16* l) {
    __builtin_amdgcn_global_load_lds((gp32)g, (lp32)l, 16, 0, 0);
}

__device__ __forceinline__ u16 f2h(float v) {
    _Float16 h = (_Float16)v;
    return *(u16*)&h;
}

// ===== kA: bx<1024 softmax (8 rows) | [1024,1536) norm+cvt+transpose 16 rows =====
__global__ __launch_bounds__(256) void kA(const float* __restrict__ logits,
        const float* __restrict__ x, float* __restrict__ wv, int* __restrict__ cls,
        float* __restrict__ inv, u16* __restrict__ zth) {
    __shared__ float xs[16 * LDA];      // 33 KB fp32 stripe (16 rows)
    __shared__ float ns[4][16];
    __shared__ float sv_s[16];
    int bx = blockIdx.x, t = threadIdx.x;
    if (bx < 1024) {
        int lane = t & 63;
        int row0 = (bx << 3) + ((t >> 6) << 1);
        #pragma unroll
        for (int rr = 0; rr < 2; ++rr) {
            int row = row0 + rr;
            const float* lrow = logits + (size_t)row * C_CLS;
            float v1 = lrow[lane];
            bool has2 = (lane + 64) < C_CLS;
            float v2 = has2 ? lrow[lane + 64] : -INFINITY;
            float m; int idx;
            if (v2 > v1) { m = v2; idx = lane + 64; } else { m = v1; idx = lane; }
            #pragma unroll
            for (int off = 32; off >= 1; off >>= 1) {
                float om = __shfl_down(m, off);
                int   oi = __shfl_down(idx, off);
                if (om > m || (om == m && oi < idx)) { m = om; idx = oi; }
            }
            m = __shfl(m, 0);
            idx = __shfl(idx, 0);
            float s = expf(v1 - m) + (has2 ? expf(v2 - m) : 0.0f);
            #pragma unroll
            for (int off = 32; off >= 1; off >>= 1) s += __shfl_down(s, off);
            if (lane == 0) {
                wv[row] = 1.0f / s;
                cls[row] = idx;
            }
        }
        return;
    }
    // -------- 16-row stripe: stage to LDS, norms, fp16 convert + transpose --
    int r0 = (bx - 1024) << 4;
    const float* src = x + (size_t)r0 * D_DIM;
    #pragma unroll
    for (int i = 0; i < 8; ++i) {
        int e = i * 1024 + t * 4;
        int r = e >> 9, c = e & 511;
        *(float4*)&xs[r * LDA + c] = *(const float4*)&src[e];
    }
    __syncthreads();
    {
        int r = t & 15, seg = t >> 4;   // 16 segs of 32
        const float* row = &xs[r * LDA + seg * 32];
        float ss = 0.f;
        #pragma unroll
        for (int jj = 0; jj < 32; ++jj) { float v = row[jj]; ss += v * v; }
        atomicAdd(&ns[seg & 3][r], 0.f);   // keep ns live (no-op)
        // 16 partials per row -> reduce via shuffle within groups of 16 threads
        // simpler: stash in LDS
        ns[0][r] = 0.f;                    // init once per row by seg 0..3 writers below
        __syncthreads();
        // accumulate 16 partials: use atomicAdd on LDS (cheap, 256 ops)
        atomicAdd(&ns[0][r], ss);
    }
    __syncthreads();
    if (t < 16) {
        float iv = 1.0f / fmaxf(sqrtf(ns[0][t]), 1e-8f);
        inv[r0 + t] = iv;
        sv_s[t] = sqrtf(iv);
    }
    __syncthreads();
    // transpose+convert: thread t handles col c = t>>1 (2 threads/col), rows rq..rq+7
    int c = t >> 1, rq = (t & 1) * 8;
    float svl[8];
    #pragma unroll
    for (int ii = 0; ii < 8; ++ii) svl[ii] = sv_s[rq + ii];
    #pragma unroll
    for (int ct = 0; ct < 4; ++ct) {
        int d = ct * 128 + c;
        u16 o[8];
        #pragma unroll
        for (int ii = 0; ii < 8; ++ii)
            o[ii] = f2h(xs[(rq + ii) * LDA + d] * svl[ii]);
        uint4 val = make_uint4((u32)o[0] | ((u32)o[1] << 16),
                               (u32)o[2] | ((u32)o[3] << 16),
                               (u32)o[4] | ((u32)o[5] << 16),
                               (u32)o[6] | ((u32)o[7] << 16));
        *(uint4*)&zth[(size_t)d * N_ROWS + r0 + rq] = val;
    }
}

// ===== kB: single-block (1024 thr) class histogram + scan + scatter =====
__global__ __launch_bounds__(1024) void kB(const int* __restrict__ cls,
        int* __restrict__ cnt, int* __restrict__ offs, int* __restrict__ order) {
    __shared__ int hist[128], scan_s[128], cur[128];
    int t = threadIdx.x;
    if (t < 128) hist[t] = 0;
    __syncthreads();
    for (int m = t; m < N_ROWS; m += 1024) atomicAdd(&hist[cls[m]], 1);
    __syncthreads();
    if (t < 128) scan_s[t] = hist[t];
    __syncthreads();
    #pragma unroll
    for (int d = 1; d < 128; d <<= 1) {
        int add = (t < 128 && t >= d) ? scan_s[t - d] : 0;
        __syncthreads();
        if (t < 128) scan_s[t] += add;
        __syncthreads();
    }
    if (t < 128) {
        int off0 = scan_s[t] - hist[t];
        cur[t] = off0;
        offs[t] = off0;
        cnt[t] = hist[t];
    }
    __syncthreads();
    for (int m = t; m < N_ROWS; m += 1024) {
        int p = atomicAdd(&cur[cls[m]], 1);
        order[p] = m;
    }
}

// ===== kC: blocks 0..319 fp16 GEMM (splitK=32, dbuf staging); 320..1119 uv ==
__global__ __launch_bounds__(256) void kC(const u16* __restrict__ zth,
        const float* __restrict__ x, const float* __restrict__ inv,
        const float* __restrict__ wv, const int* __restrict__ order,
        const int* __restrict__ offs, const int* __restrict__ cnt,
        float* __restrict__ Gp, float* __restrict__ u_arr, float* __restrict__ v_arr) {
    __shared__ __attribute__((aligned(16))) union {
        struct { u16 Ah[2][128 * 32], Bh[2][128 * 32]; } g;   // 32 KB dbuf
        struct { float us[4][64], vs[4][64]; } uv;
    } sm;
    int bx = blockIdx.x, t = threadIdx.x;
    if (bx >= 320) {
        int idx = bx - 320;
        int c = idx >> 3, jc = idx & 7;
        int g = t >> 6, lane = t & 63;
        int j = jc * 64 + lane;
        int n = cnt[c], o = offs[c];
        float ua = 0.f, va = 0.f;
        for (int p = g; p < n; p += 4) {
            int m = order[o + p];
            float wm = wv[m];
            float wi = wm * inv[m];
            float xv = x[(size_t)m * D_DIM + j];
            ua += wi * xv; va += wm * xv;
        }
        sm.uv.us[g][lane] = ua; sm.uv.vs[g][lane] = va;
        __syncthreads();
        if (g == 0) {
            u_arr[(size_t)c * D_DIM + j] = sm.uv.us[0][lane] + sm.uv.us[1][lane] + sm.uv.us[2][lane] + sm.uv.us[3][lane];
            v_arr[(size_t)c * D_DIM + j] = sm.uv.vs[0][lane] + sm.uv.vs[1][lane] + sm.uv.vs[2][lane] + sm.uv.vs[3][lane];
        }
        return;
    }
    int tile = bx % 10;
    int p = bx / 10;                    // 0..31
    int ti = tile < 4 ? 0 : (tile < 7 ? 1 : (tile < 9 ? 2 : 3));
    int tj = tile - (ti == 0 ? 0 : (ti == 1 ? 3 : (ti == 2 ? 5 : 6)));
    int i0 = ti << 7, j0 = tj << 7;
    bool diag = (ti == tj);
    int kb = p << 8;                    // K-chunk of 256
    int w = t >> 6, l = t & 63;
    int srow = t >> 2, scol = (t & 3) << 3;
    int lm = l & 15, lg = l >> 4;
    floatx4 acc[4][4];
    #pragma unroll
    for (int mi = 0; mi < 4; ++mi)
        #pragma unroll
        for (int ni = 0; ni < 4; ++ni) acc[mi][ni] = (floatx4){0.f, 0.f, 0.f, 0.f};
    int d0 = srow * 32 + scol;
    int d1 = (64 + srow) * 32 + scol;
    const size_t ga0 = (size_t)(i0 + srow) * N_ROWS + kb + scol;
    const size_t ga1 = (size_t)(i0 + 64 + srow) * N_ROWS + kb + scol;
    const size_t gb0 = (size_t)(j0 + srow) * N_ROWS + kb + scol;
    const size_t gb1 = (size_t)(j0 + 64 + srow) * N_ROWS + kb + scol;
    // prologue: stage s=0 into buffer 0
    cp16(zth + ga0, sm.g.Ah[0] + d0);
    cp16(zth + ga1, sm.g.Ah[0] + d1);
    if (!diag) {
        cp16(zth + gb0, sm.g.Bh[0] + d0);
        cp16(zth + gb1, sm.g.Bh[0] + d1);
    }
    __syncthreads();
    for (int s = 0; s < 8; ++s) {
        int cur = s & 1, nxt = cur ^ 1;
        if (s + 1 < 8) {                 // prefetch next tile (async, overlaps MFMA)
            int ks = (s + 1) << 5;
            cp16(zth + ga0 + ks, sm.g.Ah[nxt] + d0);
            cp16(zth + ga1 + ks, sm.g.Ah[nxt] + d1);
            if (!diag) {
                cp16(zth + gb0 + ks, sm.g.Bh[nxt] + d0);
                cp16(zth + gb1 + ks, sm.g.Bh[nxt] + d1);
            }
        }
        const u16* Bhs = diag ? sm.g.Ah[cur] : sm.g.Bh[cur];
        half8 ah[4], bh[4];
        #pragma unroll
        for (int mi = 0; mi < 4; ++mi) {
            int off = (((w & 1) << 6) + (mi << 4) + lm) * 32 + (lg << 3);
            ah[mi] = *(const half8*)&sm.g.Ah[cur][off];
        }
        #pragma unroll
        for (int ni = 0; ni < 4; ++ni) {
            int off = (((w >> 1) << 6) + (ni << 4) + lm) * 32 + (lg << 3);
            bh[ni] = *(const half8*)&Bhs[off];
        }
        #pragma unroll
        for (int mi = 0; mi < 4; ++mi)
            #pragma unroll
            for (int ni = 0; ni < 4; ++ni)
                acc[mi][ni] = __builtin_amdgcn_mfma_f32_16x16x32_f16(ah[mi], bh[ni], acc[mi][ni], 0, 0, 0);
        __syncthreads();                 // prefetch had full compute time in flight
    }
    float* Gb = Gp + ((size_t)(p * 10 + tile) << 14);
    #pragma unroll
    for (int mi = 0; mi < 4; ++mi) {
        int row0 = ((w & 1) << 6) + (mi << 4) + (lg << 2);
        #pragma unroll
        for (int ni = 0; ni < 4; ++ni) {
            int col = ((w >> 1) << 6) + (ni << 4) + lm;
            #pragma unroll
            for (int r = 0; r < 4; ++r)
                Gb[(size_t)(row0 + r) * 128 + col] = acc[mi][ni][r];
        }
    }
}

// ===== kR: G[r][c] = sum_p Gp[p][uppertile(r,c)] (mirror lower) =====
__global__ __launch_bounds__(256) void kR(const float* __restrict__ Gp,
                                          float* __restrict__ G) {
    int i = blockIdx.x * 256 + threadIdx.x;      // 0..262143
    int r = i >> 9, c = i & 511;
    int tr = r >> 7, tc = c >> 7, rr = r & 127, cc = c & 127;
    if (tr > tc) { int tmp = tr; tr = tc; tc = tmp; tmp = rr; rr = cc; cc = tmp; }
    int tid = tr * 4 + tc - ((tr * (tr + 1)) >> 1);
    const float* src = Gp + ((size_t)tid << 14) + rr * 128 + cc;
    float s = 0.f;
    #pragma unroll
    for (int p = 0; p < 32; ++p) s += src[(size_t)p * 163840];
    G[i] = s;
}

// ===== kD: protos, tiled for G-reuse: 13 class-groups x 16 col-panels =====
__global__ __launch_bounds__(256) void kD(const float* __restrict__ u_arr,
        const float* __restrict__ v_arr, const int* __restrict__ cnt,
        const float* __restrict__ G, float* __restrict__ out) {
    __shared__ float us[8][512];
    int g = blockIdx.x >> 4;            // 0..12
    int panel = blockIdx.x & 15;        // 0..15
    int t = threadIdx.x;
    for (int idx = t; idx < 8 * 512; idx += 256) {
        int ci = idx >> 9, k = idx & 511;
        int cc = g * 8 + ci;
        us[ci][k] = (cc < C_CLS) ? u_arr[(size_t)cc * D_DIM + k] : 0.f;
    }
    __syncthreads();
    int ci = t >> 5, cj = t & 31;
    int c = g * 8 + ci;
    int j = panel * 32 + cj;
    float acc = 0.f;
    #pragma unroll 8
    for (int k = 0; k < D_DIM; ++k)
        acc += us[ci][k] * G[(size_t)k * D_DIM + j];
    if (c < C_CLS) {
        int n = cnt[c];
        float s = (n > 0) ? 1.0f / (float)n : 0.0f;
        out[(size_t)c * D_DIM + j] = (v_arr[(size_t)c * D_DIM + j] + acc) * s;
    }
}

// ===== kE: inter[i,j,:] = proto[j] - proto[i]; 4 pairs/block =====
__global__ __launch_bounds__(256) void kE(const float* __restrict__ proto,
                                          float* __restrict__ inter) {
    int pair = blockIdx.x * 4 + (threadIdx.x >> 6);
    int i = pair / C_CLS;
    int j = pair - i * C_CLS;
    int d = (threadIdx.x & 63) << 3;
    float4 pj0 = *(const float4*)&proto[j * D_DIM + d];
    float4 pj1 = *(const float4*)&proto[j * D_DIM + d + 4];
    float4 pi0 = *(const float4*)&proto[i * D_DIM + d];
    float4 pi1 = *(const float4*)&proto[i * D_DIM + d + 4];
    float4 r0, r1;
    r0.x = pj0.x - pi0.x; r0.y = pj0.y - pi0.y; r0.z = pj0.z - pi0.z; r0.w = pj0.w - pi0.w;
    r1.x = pj1.x - pi1.x; r1.y = pj1.y - pi1.y; r1.z = pj1.z - pi1.z; r1.w = pj1.w - pi1.w;
    *(float4*)&inter[(size_t)pair * D_DIM + d]     = r0;
    *(float4*)&inter[(size_t)pair * D_DIM + d + 4] = r1;
}

extern "C" void kernel_launch(void* const* d_in, const int* in_sizes, int n_in,
                              void* d_out, int out_size, void* d_ws, size_t ws_size,
                              hipStream_t stream) {
    const float* x      = (const float*)d_in[0];   // [8192, 512]
    const float* logits = (const float*)d_in[1];   // [8192, 100]
    float* out = (float*)d_out;
    float* ws  = (float*)d_ws;
    float* G     = ws + WS_G;
    float* Gp    = ws + WS_GP;
    float* inv   = ws + WS_INV;
    float* wv    = ws + WS_WV;
    int*   cls   = (int*)(ws + WS_CLS);
    int*   cnt   = (int*)(ws + WS_CNT);
    int*   offs  = (int*)(ws + WS_OFFS);
    int*   order = (int*)(ws + WS_ORDER);
    float* u_arr = ws + WS_U;
    float* v_arr = ws + WS_V;
    u16* zth = (u16*)(ws + WS_ZTH);

    kA<<<1536, 256, 0, stream>>>(logits, x, wv, cls, inv, zth);
    kB<<<1, 1024, 0, stream>>>(cls, cnt, offs, order);
    kC<<<1120, 256, 0, stream>>>(zth, x, inv, wv, order, offs, cnt, Gp, u_arr, v_arr);
    kR<<<1024, 256, 0, stream>>>(Gp, G);
    kD<<<208, 256, 0, stream>>>(u_arr, v_arr, cnt, G, out);
    kE<<<C_CLS * C_CLS / 4, 256, 0, stream>>>(out, out + C_CLS * D_DIM);
}